// Round 8
// baseline (217.416 us; speedup 1.0000x reference)
//
#include <hip/hip_runtime.h>
#include <stddef.h>

// ---------- types ----------
typedef __bf16 bf16x8 __attribute__((ext_vector_type(8)));
typedef __bf16 bf16x4 __attribute__((ext_vector_type(4)));
typedef _Float16 f16x4 __attribute__((ext_vector_type(4)));
typedef float  f32x4  __attribute__((ext_vector_type(4)));

#define MFMA16(a, b, c) __builtin_amdgcn_mfma_f32_16x16x32_bf16((a), (b), (c), 0, 0, 0)
#define MFMA16H(a, b, c) __builtin_amdgcn_mfma_f32_16x16x16f16((a), (b), (c), 0, 0, 0)

// async global->LDS, 16B per lane; LDS dest is wave-uniform base + lane*16
__device__ __forceinline__ void gload_lds16(const void* gsrc, void* ldst) {
    __builtin_amdgcn_global_load_lds(
        (__attribute__((address_space(1))) void*)gsrc,
        (__attribute__((address_space(3))) void*)ldst,
        16, 0, 0);
}

// ---------- K0: fused prep = fp32->bf16 cast of x  +  transpose+cast of both weights ----------
__global__ void prep_kernel(const float* __restrict__ x, __bf16* __restrict__ xbf,
                            const float* __restrict__ Wqkv, __bf16* __restrict__ WqkvT,
                            const float* __restrict__ Wproj, __bf16* __restrict__ WprojT) {
    __shared__ float tile[32][33];
    const int bx = blockIdx.x, tid = threadIdx.x;
    if (bx < 3072) {                       // cast x: 786432 float4 groups
        int i = bx * 256 + tid;
        float4 v = ((const float4*)x)[i];
        bf16x4 o = {(__bf16)v.x, (__bf16)v.y, (__bf16)v.z, (__bf16)v.w};
        ((bf16x4*)xbf)[i] = o;
        return;
    }
    const float* in; __bf16* out; int R, C, c0, r0;
    if (bx < 4800) { int bb = bx - 3072; in = Wqkv;  out = WqkvT;  R = 768; C = 2304;
                     c0 = (bb % 72) * 32; r0 = (bb / 72) * 32; }
    else           { int bb = bx - 4800; in = Wproj; out = WprojT; R = 768; C = 768;
                     c0 = (bb % 24) * 32; r0 = (bb / 24) * 32; }
    const int tx = tid & 31, ty = tid >> 5;    // 32 x 8
#pragma unroll
    for (int i = 0; i < 32; i += 8)
        tile[ty + i][tx] = in[(size_t)(r0 + ty + i) * C + c0 + tx];
    __syncthreads();
#pragma unroll
    for (int i = 0; i < 32; i += 8)
        out[(size_t)(c0 + ty + i) * R + r0 + tx] = (__bf16)tile[tx][ty + i];
}

// ---------- GEMM core: 128x128 tile, BK=64, 256 threads (4 waves, each 64x64) ----------
// LDS rows are 64 elems (8 chunks of 16B); chunk c of row r stored at slot c ^ (r&7).
__device__ __forceinline__ void gemm_core_bk64(
    const __bf16* __restrict__ A, const __bf16* __restrict__ Bt, int K,
    int m0, int n0, __bf16* aT, __bf16* bT, f32x4 acc[4][4]) {
    const int tid  = threadIdx.x;
    const int wid  = tid >> 6, lane = tid & 63;
    const int quad = lane >> 4, l16 = lane & 15;
    const int wm = (wid >> 1) * 64, wn = (wid & 1) * 64;
    const int r_in = lane >> 3;                    // 0..7
    const int cswz = ((lane & 7) ^ r_in) * 8;      // swizzled k-chunk offset (elems)
    const __bf16* gA = A  + (size_t)(m0 + wid * 8 + r_in) * K + cswz;
    const __bf16* gB = Bt + (size_t)(n0 + wid * 8 + r_in) * K + cswz;
    const int sA = (l16 & 7);
    for (int k0 = 0; k0 < K; k0 += 64) {
        __syncthreads();
#pragma unroll
        for (int j = 0; j < 4; j++) {
            gload_lds16(gA + (size_t)(j * 32) * K + k0, aT + (j * 32 + wid * 8) * 64);
            gload_lds16(gB + (size_t)(j * 32) * K + k0, bT + (j * 32 + wid * 8) * 64);
        }
        __syncthreads();
#pragma unroll
        for (int kh = 0; kh < 2; kh++) {
            bf16x8 af[4], bfr[4];
#pragma unroll
            for (int t = 0; t < 4; t++) {
                const int slot = ((kh * 4 + quad) ^ sA) << 3;
                af[t]  = *(const bf16x8*)(aT + (wm + t * 16 + l16) * 64 + slot);
                bfr[t] = *(const bf16x8*)(bT + (wn + t * 16 + l16) * 64 + slot);
            }
#pragma unroll
            for (int rt = 0; rt < 4; rt++)
#pragma unroll
                for (int ct = 0; ct < 4; ct++)
                    acc[rt][ct] = MFMA16(af[rt], bfr[ct], acc[rt][ct]);
        }
    }
}

// ---------- K1: QKV GEMM, epilogue scatters to q/k (bh,s,d) bf16 and vT (bh,d,s) f16 ----------
__global__ __launch_bounds__(256, 3)
void gemm_qkv_kernel(const __bf16* __restrict__ A, const __bf16* __restrict__ Bt,
                     __bf16* __restrict__ qb, __bf16* __restrict__ kb,
                     _Float16* __restrict__ vtb) {
    __shared__ __bf16 aT[8192], bT[8192];
    f32x4 acc[4][4];
#pragma unroll
    for (int i = 0; i < 4; i++)
#pragma unroll
        for (int j = 0; j < 4; j++) { f32x4 z = {0.f, 0.f, 0.f, 0.f}; acc[i][j] = z; }
    const int m0 = blockIdx.x * 128, n0 = blockIdx.y * 128;
    gemm_core_bk64(A, Bt, 768, m0, n0, aT, bT, acc);
    const int tid = threadIdx.x, wid = tid >> 6, lane = tid & 63;
    const int quad = lane >> 4, l16 = lane & 15;
    const int wm = (wid >> 1) * 64, wn = (wid & 1) * 64;
#pragma unroll
    for (int rt = 0; rt < 4; rt++)
#pragma unroll
        for (int ct = 0; ct < 4; ct++) {
            const int ng = n0 + wn + ct * 16 + l16;
            const int which = ng / 768;
            const int rem = ng - which * 768;
            const int hh = rem >> 6, d = rem & 63;
#pragma unroll
            for (int r = 0; r < 4; r++) {
                const int mg = m0 + wm + rt * 16 + quad * 4 + r;
                const int b = mg >> 10, s = mg & 1023;
                const int bh = b * 12 + hh;
                if (which == 0)      qb[((size_t)bh * 1024 + s) * 64 + d] = (__bf16)acc[rt][ct][r];
                else if (which == 1) kb[((size_t)bh * 1024 + s) * 64 + d] = (__bf16)acc[rt][ct][r];
                else                 vtb[((size_t)bh * 64 + d) * 1024 + s] = (_Float16)acc[rt][ct][r];
            }
        }
}

// ---------- K4: proj GEMM + bias, fp32 out ----------
__global__ __launch_bounds__(256, 3)
void gemm_proj_kernel(const __bf16* __restrict__ A, const __bf16* __restrict__ Bt,
                      const float* __restrict__ bias, float* __restrict__ out) {
    __shared__ __bf16 aT[8192], bT[8192];
    f32x4 acc[4][4];
#pragma unroll
    for (int i = 0; i < 4; i++)
#pragma unroll
        for (int j = 0; j < 4; j++) { f32x4 z = {0.f, 0.f, 0.f, 0.f}; acc[i][j] = z; }
    const int m0 = blockIdx.x * 128, n0 = blockIdx.y * 128;
    gemm_core_bk64(A, Bt, 768, m0, n0, aT, bT, acc);
    const int tid = threadIdx.x, wid = tid >> 6, lane = tid & 63;
    const int quad = lane >> 4, l16 = lane & 15;
    const int wm = (wid >> 1) * 64, wn = (wid & 1) * 64;
#pragma unroll
    for (int rt = 0; rt < 4; rt++)
#pragma unroll
        for (int ct = 0; ct < 4; ct++) {
            const int ng = n0 + wn + ct * 16 + l16;
            const float bb = bias[ng];
#pragma unroll
            for (int r = 0; r < 4; r++) {
                const int mg = m0 + wm + rt * 16 + quad * 4 + r;
                out[(size_t)mg * 768 + ng] = acc[rt][ct][r] + bb;
            }
        }
}

// ---------- K3: attention v6 — S^T formulation, P stays in registers ----------
// grid (48 bh, 16 qt) [XCD-local], block 256 (4 waves), Q-tile 64, 16 rows/wave.
// S^T = MFMA(K-frag, Q-frag): C-layout col=l16=qrow, row=quad*4+r=key. That IS the
// B-fragment layout of mfma_f32_16x16x16f16 (k=quad*4+j) -> PV directly from regs:
// O^T = V^T(f16, direct global b64 loads) * P^T. No P LDS round-trip, no V staging.
// LDS: K dbuf 2x8KB (Phase-A Dw overlays it) + relh[64][33] fp32.
__global__ __launch_bounds__(256, 3)
void attn_kernel(const __bf16* __restrict__ q, const __bf16* __restrict__ kk,
                 const _Float16* __restrict__ vt, const float* __restrict__ rph,
                 const float* __restrict__ rpw, __bf16* __restrict__ aout) {
    __shared__ __bf16 kbuf2[2][4096];
    __shared__ float  relh[64][33];
    const int tid = threadIdx.x, wid = tid >> 6, lane = tid & 63;
    const int quad = lane >> 4, l16 = lane & 15;
    const int bh = blockIdx.x, qt = blockIdx.y;
    const int b = bh / 12, hh = bh - b * 12;
    const int q0 = qt * 64;
    const int w0 = wid * 16;               // wave's first row within the tile
    const int h = qt * 2 + (wid >> 1);     // wave-uniform h coordinate

    // Q fragments: lane holds Q[w0+l16][quad*8+j] — serves as B-frag (S^T) and A-frag (Phase A)
    const __bf16* qp = q + ((size_t)bh * 1024 + q0 + w0 + l16) * 64;
    bf16x8 aq0 = *(const bf16x8*)(qp + quad * 8);
    bf16x8 aq1 = *(const bf16x8*)(qp + 32 + quad * 8);

    // ---- Phase A: rel_w D-GEMM (Toeplitz) + rel_h GEMM, via MFMA ----
    float* Dw = ((float*)kbuf2) + wid * 1024;   // 16 rows x 64 cols fp32, per wave
#pragma unroll
    for (int ct = 0; ct < 4; ct++) {
        int j = ct * 16 + l16; if (j > 62) j = 62;
        const float* tb = rpw + (size_t)j * 64;
        float4 t0 = *(const float4*)(tb + quad * 8);
        float4 t1 = *(const float4*)(tb + quad * 8 + 4);
        float4 t2 = *(const float4*)(tb + 32 + quad * 8);
        float4 t3 = *(const float4*)(tb + 32 + quad * 8 + 4);
        bf16x8 b0 = {(__bf16)t0.x, (__bf16)t0.y, (__bf16)t0.z, (__bf16)t0.w,
                     (__bf16)t1.x, (__bf16)t1.y, (__bf16)t1.z, (__bf16)t1.w};
        bf16x8 b1 = {(__bf16)t2.x, (__bf16)t2.y, (__bf16)t2.z, (__bf16)t2.w,
                     (__bf16)t3.x, (__bf16)t3.y, (__bf16)t3.z, (__bf16)t3.w};
        f32x4 z = {0.f, 0.f, 0.f, 0.f};
        z = MFMA16(aq0, b0, z);
        z = MFMA16(aq1, b1, z);
#pragma unroll
        for (int i = 0; i < 4; i++)
            Dw[(quad * 4 + i) * 64 + ct * 16 + l16] = z[i];
    }
#pragma unroll
    for (int ct = 0; ct < 2; ct++) {
        const int tr = h - (ct * 16 + l16) + 31;     // in [0,62]
        const float* tb = rph + (size_t)tr * 64;
        float4 t0 = *(const float4*)(tb + quad * 8);
        float4 t1 = *(const float4*)(tb + quad * 8 + 4);
        float4 t2 = *(const float4*)(tb + 32 + quad * 8);
        float4 t3 = *(const float4*)(tb + 32 + quad * 8 + 4);
        bf16x8 b0 = {(__bf16)t0.x, (__bf16)t0.y, (__bf16)t0.z, (__bf16)t0.w,
                     (__bf16)t1.x, (__bf16)t1.y, (__bf16)t1.z, (__bf16)t1.w};
        bf16x8 b1 = {(__bf16)t2.x, (__bf16)t2.y, (__bf16)t2.z, (__bf16)t2.w,
                     (__bf16)t3.x, (__bf16)t3.y, (__bf16)t3.z, (__bf16)t3.w};
        f32x4 z = {0.f, 0.f, 0.f, 0.f};
        z = MFMA16(aq0, b0, z);
        z = MFMA16(aq1, b1, z);
#pragma unroll
        for (int i = 0; i < 4; i++)
            relh[w0 + quad * 4 + i][ct * 16 + l16] = z[i];
    }
    // gather rel_w biases for lane's qrow (= w0+l16): kw = hf*16 + quad*4 + r
    const int wq = (wid & 1) * 16 + l16;           // w coordinate of lane's qrow
    float bw[2][4];
#pragma unroll
    for (int hf = 0; hf < 2; hf++)
#pragma unroll
        for (int r = 0; r < 4; r++)
            bw[hf][r] = Dw[l16 * 64 + wq + 31 - hf * 16 - quad * 4 - r];
    __syncthreads();   // all gathers done before staging overwrites the Dw overlay

    // ---- main flash loop ----
    float l_run = 0.f;
    f32x4 o_acc[4];
#pragma unroll
    for (int t = 0; t < 4; t++) { f32x4 z = {0.f, 0.f, 0.f, 0.f}; o_acc[t] = z; }

    const __bf16*   kg0 = kk + (size_t)bh * 65536;
    const _Float16* vg0 = vt + (size_t)bh * 65536 + (size_t)l16 * 1024 + quad * 4;
    const int cbase = wid * 2;                         // 4 waves stage 2 chunks each
    const int srow = lane >> 3;
    const int scol = ((lane & 7) ^ srow) * 8;          // swizzled global chunk
    const int swz0 = ((quad ^ (l16 & 7)) << 3);
    const int swz1 = (((quad | 4) ^ (l16 & 7)) << 3);

    auto stageK = [&](int buf, int kt) {
        const __bf16* kg = kg0 + kt * 4096;
        __bf16* kb_ = &kbuf2[buf][0];
#pragma unroll
        for (int j = 0; j < 2; j++) {
            const int c = cbase + j;
            gload_lds16(kg + (c * 8 + srow) * 64 + scol, kb_ + c * 512);
        }
    };

    stageK(0, 0);
    for (int kt = 0; kt < 16; kt++) {
        const int cur = kt & 1;
        __syncthreads();                 // drains cur's staging
        if (kt < 15) stageK(1 - cur, kt + 1);
        const __bf16* kbuf = &kbuf2[cur][0];

        // V fragments direct from global (L1/L2-local): vf[dt][ct] = V^T[dt*16+l16][kt*64+ct*16+quad*4..+3]
        f16x4 vf[4][4];
#pragma unroll
        for (int dt = 0; dt < 4; dt++) {
            const _Float16* vp = vg0 + (size_t)dt * 16384 + kt * 64;
#pragma unroll
            for (int ct = 0; ct < 4; ct++)
                vf[dt][ct] = *(const f16x4*)(vp + ct * 16);
        }

        // S^T = K-frag (A) x Q-frag (B)
        f32x4 sacc[4];
#pragma unroll
        for (int ct = 0; ct < 4; ct++) {
            const int key = ct * 16 + l16;
            bf16x8 bk0 = *(const bf16x8*)(kbuf + key * 64 + swz0);
            bf16x8 bk1 = *(const bf16x8*)(kbuf + key * 64 + swz1);
            f32x4 z = {0.f, 0.f, 0.f, 0.f};
            z = MFMA16(bk0, aq0, z);
            z = MFMA16(bk1, aq1, z);
            sacc[ct] = z;
        }

        // bias + exp; pack P^T fragments (f16) straight from registers
        const float bh0 = relh[w0 + l16][kt * 2];
        const float bh1 = relh[w0 + l16][kt * 2 + 1];
        f16x4 pf[4];
#pragma unroll
        for (int ct = 0; ct < 4; ct++) {
            const float bhc = (ct < 2) ? bh0 : bh1;
#pragma unroll
            for (int r = 0; r < 4; r++) {
                float sv = fmaf(sacc[ct][r], 0.125f, bhc + bw[ct & 1][r]);
                float p = __expf(sv);
                l_run += p;
                pf[ct][r] = (_Float16)p;
            }
        }

        // O^T += V^T * P^T  (16x16x16 f16 MFMAs)
#pragma unroll
        for (int dt = 0; dt < 4; dt++)
#pragma unroll
            for (int ct = 0; ct < 4; ct++)
                o_acc[dt] = MFMA16H(vf[dt][ct], pf[ct], o_acc[dt]);
    }

    // reduce row sum across the 4 quads holding the same qrow, then normalize & store
    l_run += __shfl_xor(l_run, 16);
    l_run += __shfl_xor(l_run, 32);
    const float inv = 1.f / l_run;
    const int srow_o = q0 + w0 + l16;
    float* obase_chk; (void)obase_chk;
#pragma unroll
    for (int dt = 0; dt < 4; dt++) {
        bf16x4 ov = {(__bf16)(o_acc[dt][0] * inv), (__bf16)(o_acc[dt][1] * inv),
                     (__bf16)(o_acc[dt][2] * inv), (__bf16)(o_acc[dt][3] * inv)};
        *(bf16x4*)&aout[((size_t)b * 1024 + srow_o) * 768 + hh * 64 + dt * 16 + quad * 4] = ov;
    }
}

// ---------- launch ----------
extern "C" void kernel_launch(void* const* d_in, const int* in_sizes, int n_in,
                              void* d_out, int out_size, void* d_ws, size_t ws_size,
                              hipStream_t stream) {
    const float* x     = (const float*)d_in[0];
    const float* Wqkv  = (const float*)d_in[1];
    const float* Wproj = (const float*)d_in[2];
    const float* bproj = (const float*)d_in[3];
    const float* rph   = (const float*)d_in[4];
    const float* rpw   = (const float*)d_in[5];
    float* out = (float*)d_out;
    char* ws = (char*)d_ws;

    __bf16*   xbf    = (__bf16*)(ws);                 // 4096*768*2   = 6291456
    __bf16*   WqkvT  = (__bf16*)(ws + 6291456);       // 2304*768*2   = 3538944
    __bf16*   WprojT = (__bf16*)(ws + 9830400);       // 768*768*2    = 1179648
    __bf16*   qb     = (__bf16*)(ws + 11010048);      // 48*1024*64*2 = 6291456
    __bf16*   kb     = (__bf16*)(ws + 17301504);      // 6291456
    _Float16* vtb    = (_Float16*)(ws + 23592960);    // 6291456
    __bf16*   aob    = (__bf16*)(ws + 29884416);      // 4096*768*2   = 6291456
    // total 36175872 bytes

    prep_kernel<<<dim3(5376), dim3(256), 0, stream>>>(x, xbf, Wqkv, WqkvT, Wproj, WprojT);
    gemm_qkv_kernel<<<dim3(32, 18), dim3(256), 0, stream>>>(xbf, WqkvT, qb, kb, vtb);
    attn_kernel<<<dim3(48, 16), dim3(256), 0, stream>>>(qb, kb, vtb, rph, rpw, aob);
    gemm_proj_kernel<<<dim3(32, 6), dim3(256), 0, stream>>>(aob, WprojT, bproj, out);
}

// Round 9
// 150.526 us; speedup vs baseline: 1.4444x; 1.4444x over previous
//
#include <hip/hip_runtime.h>
#include <stddef.h>

// ---------- types ----------
typedef __bf16 bf16x8 __attribute__((ext_vector_type(8)));
typedef __bf16 bf16x4 __attribute__((ext_vector_type(4)));
typedef _Float16 f16x4 __attribute__((ext_vector_type(4)));
typedef float  f32x4  __attribute__((ext_vector_type(4)));

#define MFMA16(a, b, c) __builtin_amdgcn_mfma_f32_16x16x32_bf16((a), (b), (c), 0, 0, 0)
#define MFMA16H(a, b, c) __builtin_amdgcn_mfma_f32_16x16x16f16((a), (b), (c), 0, 0, 0)

// async global->LDS, 16B per lane; LDS dest is wave-uniform base + lane*16
__device__ __forceinline__ void gload_lds16(const void* gsrc, void* ldst) {
    __builtin_amdgcn_global_load_lds(
        (__attribute__((address_space(1))) void*)gsrc,
        (__attribute__((address_space(3))) void*)ldst,
        16, 0, 0);
}

// ---------- K0: fused prep = fp32->bf16 cast of x  +  transpose+cast of both weights ----------
__global__ void prep_kernel(const float* __restrict__ x, __bf16* __restrict__ xbf,
                            const float* __restrict__ Wqkv, __bf16* __restrict__ WqkvT,
                            const float* __restrict__ Wproj, __bf16* __restrict__ WprojT) {
    __shared__ float tile[32][33];
    const int bx = blockIdx.x, tid = threadIdx.x;
    if (bx < 3072) {                       // cast x: 786432 float4 groups
        int i = bx * 256 + tid;
        float4 v = ((const float4*)x)[i];
        bf16x4 o = {(__bf16)v.x, (__bf16)v.y, (__bf16)v.z, (__bf16)v.w};
        ((bf16x4*)xbf)[i] = o;
        return;
    }
    const float* in; __bf16* out; int R, C, c0, r0;
    if (bx < 4800) { int bb = bx - 3072; in = Wqkv;  out = WqkvT;  R = 768; C = 2304;
                     c0 = (bb % 72) * 32; r0 = (bb / 72) * 32; }
    else           { int bb = bx - 4800; in = Wproj; out = WprojT; R = 768; C = 768;
                     c0 = (bb % 24) * 32; r0 = (bb / 24) * 32; }
    const int tx = tid & 31, ty = tid >> 5;    // 32 x 8
#pragma unroll
    for (int i = 0; i < 32; i += 8)
        tile[ty + i][tx] = in[(size_t)(r0 + ty + i) * C + c0 + tx];
    __syncthreads();
#pragma unroll
    for (int i = 0; i < 32; i += 8)
        out[(size_t)(c0 + ty + i) * R + r0 + tx] = (__bf16)tile[tx][ty + i];
}

// ---------- GEMM core: 128x128 tile, BK=64, 256 threads (4 waves, each 64x64) ----------
// LDS rows are 64 elems (8 chunks of 16B); chunk c of row r stored at slot c ^ (r&7).
__device__ __forceinline__ void gemm_core_bk64(
    const __bf16* __restrict__ A, const __bf16* __restrict__ Bt, int K,
    int m0, int n0, __bf16* aT, __bf16* bT, f32x4 acc[4][4]) {
    const int tid  = threadIdx.x;
    const int wid  = tid >> 6, lane = tid & 63;
    const int quad = lane >> 4, l16 = lane & 15;
    const int wm = (wid >> 1) * 64, wn = (wid & 1) * 64;
    const int r_in = lane >> 3;                    // 0..7
    const int cswz = ((lane & 7) ^ r_in) * 8;      // swizzled k-chunk offset (elems)
    const __bf16* gA = A  + (size_t)(m0 + wid * 8 + r_in) * K + cswz;
    const __bf16* gB = Bt + (size_t)(n0 + wid * 8 + r_in) * K + cswz;
    const int sA = (l16 & 7);
    for (int k0 = 0; k0 < K; k0 += 64) {
        __syncthreads();
#pragma unroll
        for (int j = 0; j < 4; j++) {
            gload_lds16(gA + (size_t)(j * 32) * K + k0, aT + (j * 32 + wid * 8) * 64);
            gload_lds16(gB + (size_t)(j * 32) * K + k0, bT + (j * 32 + wid * 8) * 64);
        }
        __syncthreads();
#pragma unroll
        for (int kh = 0; kh < 2; kh++) {
            bf16x8 af[4], bfr[4];
#pragma unroll
            for (int t = 0; t < 4; t++) {
                const int slot = ((kh * 4 + quad) ^ sA) << 3;
                af[t]  = *(const bf16x8*)(aT + (wm + t * 16 + l16) * 64 + slot);
                bfr[t] = *(const bf16x8*)(bT + (wn + t * 16 + l16) * 64 + slot);
            }
#pragma unroll
            for (int rt = 0; rt < 4; rt++)
#pragma unroll
                for (int ct = 0; ct < 4; ct++)
                    acc[rt][ct] = MFMA16(af[rt], bfr[ct], acc[rt][ct]);
        }
    }
}

// ---------- K1: QKV GEMM, epilogue scatters to q/k (bh,s,d) bf16 and vT (bh,d,s) f16 ----------
__global__ __launch_bounds__(256, 3)
void gemm_qkv_kernel(const __bf16* __restrict__ A, const __bf16* __restrict__ Bt,
                     __bf16* __restrict__ qb, __bf16* __restrict__ kb,
                     _Float16* __restrict__ vtb) {
    __shared__ __bf16 aT[8192], bT[8192];
    f32x4 acc[4][4];
#pragma unroll
    for (int i = 0; i < 4; i++)
#pragma unroll
        for (int j = 0; j < 4; j++) { f32x4 z = {0.f, 0.f, 0.f, 0.f}; acc[i][j] = z; }
    const int m0 = blockIdx.x * 128, n0 = blockIdx.y * 128;
    gemm_core_bk64(A, Bt, 768, m0, n0, aT, bT, acc);
    const int tid = threadIdx.x, wid = tid >> 6, lane = tid & 63;
    const int quad = lane >> 4, l16 = lane & 15;
    const int wm = (wid >> 1) * 64, wn = (wid & 1) * 64;
#pragma unroll
    for (int rt = 0; rt < 4; rt++)
#pragma unroll
        for (int ct = 0; ct < 4; ct++) {
            const int ng = n0 + wn + ct * 16 + l16;
            const int which = ng / 768;
            const int rem = ng - which * 768;
            const int hh = rem >> 6, d = rem & 63;
#pragma unroll
            for (int r = 0; r < 4; r++) {
                const int mg = m0 + wm + rt * 16 + quad * 4 + r;
                const int b = mg >> 10, s = mg & 1023;
                const int bh = b * 12 + hh;
                if (which == 0)      qb[((size_t)bh * 1024 + s) * 64 + d] = (__bf16)acc[rt][ct][r];
                else if (which == 1) kb[((size_t)bh * 1024 + s) * 64 + d] = (__bf16)acc[rt][ct][r];
                else                 vtb[((size_t)bh * 64 + d) * 1024 + s] = (_Float16)acc[rt][ct][r];
            }
        }
}

// ---------- K4: proj GEMM + bias, fp32 out ----------
__global__ __launch_bounds__(256, 3)
void gemm_proj_kernel(const __bf16* __restrict__ A, const __bf16* __restrict__ Bt,
                      const float* __restrict__ bias, float* __restrict__ out) {
    __shared__ __bf16 aT[8192], bT[8192];
    f32x4 acc[4][4];
#pragma unroll
    for (int i = 0; i < 4; i++)
#pragma unroll
        for (int j = 0; j < 4; j++) { f32x4 z = {0.f, 0.f, 0.f, 0.f}; acc[i][j] = z; }
    const int m0 = blockIdx.x * 128, n0 = blockIdx.y * 128;
    gemm_core_bk64(A, Bt, 768, m0, n0, aT, bT, acc);
    const int tid = threadIdx.x, wid = tid >> 6, lane = tid & 63;
    const int quad = lane >> 4, l16 = lane & 15;
    const int wm = (wid >> 1) * 64, wn = (wid & 1) * 64;
#pragma unroll
    for (int rt = 0; rt < 4; rt++)
#pragma unroll
        for (int ct = 0; ct < 4; ct++) {
            const int ng = n0 + wn + ct * 16 + l16;
            const float bb = bias[ng];
#pragma unroll
            for (int r = 0; r < 4; r++) {
                const int mg = m0 + wm + rt * 16 + quad * 4 + r;
                out[(size_t)mg * 768 + ng] = acc[rt][ct][r] + bb;
            }
        }
}

// ---------- K3: attention v7 — S^T formulation, P in registers, V staged in LDS (f16) ----------
// grid (48 bh, 16 qt) [XCD-local], block 256 (4 waves), Q-tile 64, 16 rows/wave.
// S^T = MFMA(K-frag, Q-frag): C-layout col=l16=qrow, row=quad*4+r=key — exactly the
// B-frag layout of mfma_f32_16x16x16f16 (k=quad*4+j) -> PV from registers, no P LDS trip.
// K LDS: (key,d) bf16, chunk c of row stored at c^(key&7). V LDS: (d,key) f16, chunk
// kc of row d stored at kc^(d&7) -> b64 A-frag reads are 2-way conflict (free).
// Phase A overlays the K dbuf (16 KB) with Dw[wave][16r][64j] fp32 for rel_w gather.
__global__ __launch_bounds__(256, 3)
void attn_kernel(const __bf16* __restrict__ q, const __bf16* __restrict__ kk,
                 const _Float16* __restrict__ vt, const float* __restrict__ rph,
                 const float* __restrict__ rpw, __bf16* __restrict__ aout) {
    __shared__ __bf16   kbuf2[2][4096];
    __shared__ _Float16 vbuf2[2][4096];
    __shared__ float    relh[64][33];
    const int tid = threadIdx.x, wid = tid >> 6, lane = tid & 63;
    const int quad = lane >> 4, l16 = lane & 15;
    const int bh = blockIdx.x, qt = blockIdx.y;
    const int b = bh / 12, hh = bh - b * 12;
    const int q0 = qt * 64;
    const int w0 = wid * 16;               // wave's first row within the tile
    const int h = qt * 2 + (wid >> 1);     // wave-uniform h coordinate

    // Q fragments: lane holds Q[w0+l16][quad*8+j] — B-frag for S^T, A-frag for Phase A
    const __bf16* qp = q + ((size_t)bh * 1024 + q0 + w0 + l16) * 64;
    bf16x8 aq0 = *(const bf16x8*)(qp + quad * 8);
    bf16x8 aq1 = *(const bf16x8*)(qp + 32 + quad * 8);

    // ---- Phase A: rel_w D-GEMM (Toeplitz) + rel_h GEMM, via MFMA ----
    float* Dw = ((float*)kbuf2) + wid * 1024;   // 16 rows x 64 cols fp32, per wave
#pragma unroll
    for (int ct = 0; ct < 4; ct++) {
        int j = ct * 16 + l16; if (j > 62) j = 62;
        const float* tb = rpw + (size_t)j * 64;
        float4 t0 = *(const float4*)(tb + quad * 8);
        float4 t1 = *(const float4*)(tb + quad * 8 + 4);
        float4 t2 = *(const float4*)(tb + 32 + quad * 8);
        float4 t3 = *(const float4*)(tb + 32 + quad * 8 + 4);
        bf16x8 b0 = {(__bf16)t0.x, (__bf16)t0.y, (__bf16)t0.z, (__bf16)t0.w,
                     (__bf16)t1.x, (__bf16)t1.y, (__bf16)t1.z, (__bf16)t1.w};
        bf16x8 b1 = {(__bf16)t2.x, (__bf16)t2.y, (__bf16)t2.z, (__bf16)t2.w,
                     (__bf16)t3.x, (__bf16)t3.y, (__bf16)t3.z, (__bf16)t3.w};
        f32x4 z = {0.f, 0.f, 0.f, 0.f};
        z = MFMA16(aq0, b0, z);
        z = MFMA16(aq1, b1, z);
#pragma unroll
        for (int i = 0; i < 4; i++)
            Dw[(quad * 4 + i) * 64 + ct * 16 + l16] = z[i];
    }
#pragma unroll
    for (int ct = 0; ct < 2; ct++) {
        const int tr = h - (ct * 16 + l16) + 31;     // in [0,62]
        const float* tb = rph + (size_t)tr * 64;
        float4 t0 = *(const float4*)(tb + quad * 8);
        float4 t1 = *(const float4*)(tb + quad * 8 + 4);
        float4 t2 = *(const float4*)(tb + 32 + quad * 8);
        float4 t3 = *(const float4*)(tb + 32 + quad * 8 + 4);
        bf16x8 b0 = {(__bf16)t0.x, (__bf16)t0.y, (__bf16)t0.z, (__bf16)t0.w,
                     (__bf16)t1.x, (__bf16)t1.y, (__bf16)t1.z, (__bf16)t1.w};
        bf16x8 b1 = {(__bf16)t2.x, (__bf16)t2.y, (__bf16)t2.z, (__bf16)t2.w,
                     (__bf16)t3.x, (__bf16)t3.y, (__bf16)t3.z, (__bf16)t3.w};
        f32x4 z = {0.f, 0.f, 0.f, 0.f};
        z = MFMA16(aq0, b0, z);
        z = MFMA16(aq1, b1, z);
#pragma unroll
        for (int i = 0; i < 4; i++)
            relh[w0 + quad * 4 + i][ct * 16 + l16] = z[i];
    }
    // gather rel_w biases for lane's qrow (= w0+l16): kw = hf*16 + quad*4 + r
    const int wq = (wid & 1) * 16 + l16;           // w coordinate of lane's qrow
    float bw[2][4];
#pragma unroll
    for (int hf = 0; hf < 2; hf++)
#pragma unroll
        for (int r = 0; r < 4; r++)
            bw[hf][r] = Dw[l16 * 64 + wq + 31 - hf * 16 - quad * 4 - r];
    __syncthreads();   // all gathers done before staging overwrites the Dw overlay

    // ---- main flash loop ----
    float l_run = 0.f;
    f32x4 o_acc[4];
#pragma unroll
    for (int t = 0; t < 4; t++) { f32x4 z = {0.f, 0.f, 0.f, 0.f}; o_acc[t] = z; }

    const __bf16*   kg0 = kk + (size_t)bh * 65536;
    const _Float16* vg0 = vt + (size_t)bh * 65536;
    const int cbase = wid * 2;                         // 4 waves stage 2 chunks each
    const int srow = lane >> 3;
    const int scol = ((lane & 7) ^ srow) * 8;          // swizzled chunk (8 elems of 16B/8)
    const int swz0 = ((quad ^ (l16 & 7)) << 3);
    const int swz1 = (((quad | 4) ^ (l16 & 7)) << 3);
    const int l7 = l16 & 7, qhi = quad >> 1, qlo = (quad & 1) * 4;

    auto stage = [&](int buf, int kt) {
        const __bf16*   kg = kg0 + kt * 4096;
        const _Float16* vg = vg0 + kt * 64;
        __bf16*   kb_ = &kbuf2[buf][0];
        _Float16* vb_ = &vbuf2[buf][0];
#pragma unroll
        for (int j = 0; j < 2; j++) {
            const int c = cbase + j;
            gload_lds16(kg + (c * 8 + srow) * 64 + scol, kb_ + c * 512);
            gload_lds16(vg + (size_t)(c * 8 + srow) * 1024 + scol, vb_ + c * 512);
        }
    };

    stage(0, 0);
    for (int kt = 0; kt < 16; kt++) {
        const int cur = kt & 1;
        __syncthreads();                 // drains cur's staging
        if (kt < 15) stage(1 - cur, kt + 1);
        const __bf16*   kbuf = &kbuf2[cur][0];
        const _Float16* vbuf = &vbuf2[cur][0];

        // S^T = K-frag (A) x Q-frag (B)
        f32x4 sacc[4];
#pragma unroll
        for (int ct = 0; ct < 4; ct++) {
            const int key = ct * 16 + l16;
            bf16x8 bk0 = *(const bf16x8*)(kbuf + key * 64 + swz0);
            bf16x8 bk1 = *(const bf16x8*)(kbuf + key * 64 + swz1);
            f32x4 z = {0.f, 0.f, 0.f, 0.f};
            z = MFMA16(bk0, aq0, z);
            z = MFMA16(bk1, aq1, z);
            sacc[ct] = z;
        }

        // bias + exp; pack P^T fragments (f16) straight from registers
        const float bh0 = relh[w0 + l16][kt * 2];
        const float bh1 = relh[w0 + l16][kt * 2 + 1];
        f16x4 pf[4];
#pragma unroll
        for (int ct = 0; ct < 4; ct++) {
            const float bhc = (ct < 2) ? bh0 : bh1;
#pragma unroll
            for (int r = 0; r < 4; r++) {
                float sv = fmaf(sacc[ct][r], 0.125f, bhc + bw[ct & 1][r]);
                float p = __expf(sv);
                l_run += p;
                pf[ct][r] = (_Float16)p;
            }
        }

        // O^T += V^T * P^T  (16x16x16 f16 MFMAs, V A-frags via b64 LDS reads)
#pragma unroll
        for (int dt = 0; dt < 4; dt++) {
            const int vrow = (dt * 16 + l16) * 64;
#pragma unroll
            for (int ct = 0; ct < 4; ct++) {
                const int slot = (ct * 2 + qhi) ^ l7;
                f16x4 vf = *(const f16x4*)(vbuf + vrow + slot * 8 + qlo);
                o_acc[dt] = MFMA16H(vf, pf[ct], o_acc[dt]);
            }
        }
    }

    // reduce row sum across the 4 quads holding the same qrow, then normalize & store
    l_run += __shfl_xor(l_run, 16);
    l_run += __shfl_xor(l_run, 32);
    const float inv = 1.f / l_run;
    const int srow_o = q0 + w0 + l16;
#pragma unroll
    for (int dt = 0; dt < 4; dt++) {
        bf16x4 ov = {(__bf16)(o_acc[dt][0] * inv), (__bf16)(o_acc[dt][1] * inv),
                     (__bf16)(o_acc[dt][2] * inv), (__bf16)(o_acc[dt][3] * inv)};
        *(bf16x4*)&aout[((size_t)b * 1024 + srow_o) * 768 + hh * 64 + dt * 16 + quad * 4] = ov;
    }
}

// ---------- launch ----------
extern "C" void kernel_launch(void* const* d_in, const int* in_sizes, int n_in,
                              void* d_out, int out_size, void* d_ws, size_t ws_size,
                              hipStream_t stream) {
    const float* x     = (const float*)d_in[0];
    const float* Wqkv  = (const float*)d_in[1];
    const float* Wproj = (const float*)d_in[2];
    const float* bproj = (const float*)d_in[3];
    const float* rph   = (const float*)d_in[4];
    const float* rpw   = (const float*)d_in[5];
    float* out = (float*)d_out;
    char* ws = (char*)d_ws;

    __bf16*   xbf    = (__bf16*)(ws);                 // 4096*768*2   = 6291456
    __bf16*   WqkvT  = (__bf16*)(ws + 6291456);       // 2304*768*2   = 3538944
    __bf16*   WprojT = (__bf16*)(ws + 9830400);       // 768*768*2    = 1179648
    __bf16*   qb     = (__bf16*)(ws + 11010048);      // 48*1024*64*2 = 6291456
    __bf16*   kb     = (__bf16*)(ws + 17301504);      // 6291456
    _Float16* vtb    = (_Float16*)(ws + 23592960);    // 6291456
    __bf16*   aob    = (__bf16*)(ws + 29884416);      // 4096*768*2   = 6291456
    // total 36175872 bytes

    prep_kernel<<<dim3(5376), dim3(256), 0, stream>>>(x, xbf, Wqkv, WqkvT, Wproj, WprojT);
    gemm_qkv_kernel<<<dim3(32, 18), dim3(256), 0, stream>>>(xbf, WqkvT, qb, kb, vtb);
    attn_kernel<<<dim3(48, 16), dim3(256), 0, stream>>>(qb, kb, vtb, rph, rpw, aob);
    gemm_proj_kernel<<<dim3(32, 6), dim3(256), 0, stream>>>(aob, WprojT, bproj, out);
}